// Round 15
// baseline (14.617 us; speedup 1.0000x reference)
//
#include <hip/hip_runtime.h>

// MetaSR scale-4 as MFMA GEMM: out[48][4096] = W[48][576] @ U[576][4096].
// 16 distinct MLP inputs (exact in fp32) -> W rows m = s*3+k, K reordered
// k = tap*64 + c so B-fragments build in registers from L2/HBM.
// R14: k_predw computes 4 subpixels per w2 load (4x fewer load instrs,
// w2 walked 4x not 16x); k_conv drops branches in the K-split loop
// (clamp+mask) so all loads pipeline. Residual time vs model measures the
// graph-launch floor (~10us per rocprof.md).

#define NOUT 1728

typedef short bf16x8 __attribute__((ext_vector_type(8)));
typedef float f32x4  __attribute__((ext_vector_type(4)));

__device__ inline unsigned short bf16r(float a) {
    const unsigned ua = __builtin_bit_cast(unsigned, a);
    return (unsigned short)((ua + 0x7FFFu + ((ua >> 16) & 1u)) >> 16);
}
__device__ inline unsigned bf16pack(float a, float b) {
    unsigned ua = __builtin_bit_cast(unsigned, a);
    unsigned ub = __builtin_bit_cast(unsigned, b);
    ua = (ua + 0x7FFFu + ((ua >> 16) & 1u)) >> 16;
    ub = (ub + 0x7FFFu + ((ub >> 16) & 1u)) >> 16;
    return ua | (ub << 16);
}

// ---------------- Kernel 1: W bf16, layout [m=48][k=tap*64+c] --------------
// grid 108 = 4 sgroups x 27 chunks; block 256 = 64 outputs x 4 K-quarters.
// Each thread: 64 w2 loads shared across 4 subpixels (acc[4]).
__global__ __launch_bounds__(256, 2) void k_predw(
    const float* __restrict__ w1, const float* __restrict__ b1,
    const float* __restrict__ w2, const float* __restrict__ b2,
    unsigned short* __restrict__ predw16)
{
    __shared__ float h4[4][256];
    __shared__ float red[1024];            // [(q*64+o_l)*4 + si]

    const int tid   = threadIdx.x;
    const int sg    = blockIdx.x / 27;     // 0..3 (s = sg*4 + si)
    const int chunk = blockIdx.x - sg * 27;
    const int o_l   = tid & 63;
    const int q     = tid >> 6;            // K-quarter
    const int o     = chunk * 64 + o_l;    // 0..1727

    // h for the 4 subpixels of this group
    {
        const float wa = w1[tid];
        const float wb = w1[256 + tid];
        const float wc = w1[512 + tid];
        const float bb = b1[tid];
        #pragma unroll
        for (int si = 0; si < 4; ++si) {
            const int s = (sg << 2) + si;
            const float rel0 = (float)(s >> 2) * 0.25f;
            const float rel1 = (float)(s & 3) * 0.25f;
            h4[si][tid] = fmaxf(fmaf(wa, rel0, fmaf(wb, rel1,
                                fmaf(wc, 0.25f, bb))), 0.0f);
        }
    }
    __syncthreads();

    const float* w2c = w2 + (q << 6) * NOUT + o;
    const float* hq0 = &h4[0][q << 6];
    const float* hq1 = &h4[1][q << 6];
    const float* hq2 = &h4[2][q << 6];
    const float* hq3 = &h4[3][q << 6];

    float a0 = 0.f, a1 = 0.f, a2 = 0.f, a3 = 0.f;
    #pragma unroll 16
    for (int j = 0; j < 64; ++j) {
        const float v = w2c[j * NOUT];
        a0 = fmaf(hq0[j], v, a0);          // LDS same-addr broadcast
        a1 = fmaf(hq1[j], v, a1);
        a2 = fmaf(hq2[j], v, a2);
        a3 = fmaf(hq3[j], v, a3);
    }

    *(float4*)&red[tid << 2] = make_float4(a0, a1, a2, a3);
    __syncthreads();

    // 256 threads: (o_l, si); sum q ascending (same order as before)
    {
        const int ol = tid >> 2;
        const int si = tid & 3;
        const int oo = chunk * 64 + ol;
        float a = red[(0 * 64 + ol) * 4 + si] + red[(1 * 64 + ol) * 4 + si]
                + red[(2 * 64 + ol) * 4 + si] + red[(3 * 64 + ol) * 4 + si]
                + b2[oo];
        const int ct = oo / 3;
        const int k  = oo - ct * 3;
        const int c  = (ct * 7282) >> 16;  // ct/9 exact for ct<576
        const int tp = ct - c * 9;
        const int m  = ((sg << 2) + si) * 3 + k;
        predw16[m * 576 + tp * 64 + c] = bf16r(a);
    }
}

// ---------------- Kernel 2: MFMA conv, 4-wave K-split, branch-free ---------
// grid 768: mt = bid>>8, nt = bid&255; block 256 = 4 waves, wave w: kk=w+4i
__global__ __launch_bounds__(256, 1) void k_conv(
    const float* __restrict__ feat, const unsigned short* __restrict__ predw16,
    float* __restrict__ out)
{
    __shared__ f32x4 red[3 * 64];          // partials of waves 1..3

    const int tid  = threadIdx.x;
    const int lane = tid & 63;
    const int w    = tid >> 6;            // K-split wave 0..3
    const int bid  = blockIdx.x;
    const int mt   = bid >> 8;            // m-tile 0..2
    const int nt   = bid & 255;           // n-tile 0..255
    const int y0   = nt >> 2;
    const int x0   = (nt & 3) << 4;

    const int lc = lane & 15;             // B col (cell) / A row (m)
    const int lk = lane >> 4;             // k subgroup 0..3

    int xadr[3]; float xmsk[3];
    #pragma unroll
    for (int d = 0; d < 3; ++d) {
        const int rx = x0 + lc + d - 1;
        xmsk[d] = ((unsigned)rx < 64u) ? 1.0f : 0.0f;
        xadr[d] = rx < 0 ? 0 : (rx > 63 ? 63 : rx);
    }
    int yadr[3]; float ymsk[3];
    #pragma unroll
    for (int d = 0; d < 3; ++d) {
        const int ry = y0 + d - 1;
        ymsk[d] = ((unsigned)ry < 64u) ? 1.0f : 0.0f;
        yadr[d] = (ry < 0 ? 0 : (ry > 63 ? 63 : ry)) << 6;
    }

    const unsigned short* arow = predw16 + (mt * 16 + lc) * 576 + (lk << 3);

    f32x4 acc = {0.0f, 0.0f, 0.0f, 0.0f};

    #pragma unroll
    for (int i = 0; i < 5; ++i) {
        const int kk  = w + (i << 2);               // 0..19
        const int kkc = kk > 17 ? 17 : kk;          // clamp (addr-safe)
        const float vld = (kk < 18) ? 1.0f : 0.0f;  // mask instead of branch
        const int tap = kkc >> 1;
        const int dr  = (tap >= 6) ? 2 : (tap >= 3 ? 1 : 0);
        const int dc  = tap - dr * 3;
        const int c0  = ((kkc & 1) << 5) + (lk << 3);
        const float* fb = feat + (c0 << 12) + yadr[dr] + xadr[dc];
        const float  mk = ymsk[dr] * xmsk[dc] * vld;

        const float v0 = fb[0]       * mk;
        const float v1 = fb[1 << 12] * mk;
        const float v2 = fb[2 << 12] * mk;
        const float v3 = fb[3 << 12] * mk;
        const float v4 = fb[4 << 12] * mk;
        const float v5 = fb[5 << 12] * mk;
        const float v6 = fb[6 << 12] * mk;
        const float v7 = fb[7 << 12] * mk;

        uint4 bb;
        bb.x = bf16pack(v0, v1);
        bb.y = bf16pack(v2, v3);
        bb.z = bf16pack(v4, v5);
        bb.w = bf16pack(v6, v7);
        const bf16x8 bfrag = __builtin_bit_cast(bf16x8, bb);
        const bf16x8 afrag = *(const bf16x8*)(arow + 32 * kkc);

        acc = __builtin_amdgcn_mfma_f32_16x16x32_bf16(afrag, bfrag, acc,
                                                      0, 0, 0);
    }

    // 4-wave fp32 reduce (fixed order -> deterministic)
    if (w > 0) red[(w - 1) * 64 + lane] = acc;
    __syncthreads();

    if (w == 0) {
        #pragma unroll
        for (int q = 0; q < 3; ++q) {
            const f32x4 v = red[q * 64 + lane];
            acc[0] += v[0]; acc[1] += v[1]; acc[2] += v[2]; acc[3] += v[3];
        }
        #pragma unroll
        for (int r = 0; r < 4; ++r) {
            const int m = mt * 16 + (lk << 2) + r;
            const int s = (m * 171) >> 9;  // m/3 exact for m<48
            const int k = m - s * 3;
            const int y = (y0 << 2) + (s >> 2);
            const int x = ((x0 + lc) << 2) + (s & 3);
            out[k * 65536 + y * 256 + x] = acc[r];
        }
    }
}

extern "C" void kernel_launch(void* const* d_in, const int* in_sizes, int n_in,
                              void* d_out, int out_size, void* d_ws, size_t ws_size,
                              hipStream_t stream) {
    const float* feat = (const float*)d_in[0];
    const float* w1   = (const float*)d_in[1];
    const float* b1   = (const float*)d_in[2];
    const float* w2   = (const float*)d_in[3];
    const float* b2   = (const float*)d_in[4];
    float* out = (float*)d_out;
    unsigned short* predw16 = (unsigned short*)d_ws;  // 48*576*2 = 55296 B

    hipLaunchKernelGGL(k_predw, dim3(108), dim3(256), 0, stream,
                       w1, b1, w2, b2, predw16);
    hipLaunchKernelGGL(k_conv, dim3(768), dim3(256), 0, stream,
                       feat, predw16, out);
}